// Round 1
// baseline (954.056 us; speedup 1.0000x reference)
//
#include <hip/hip_runtime.h>
#include <stdint.h>

#define NB 2
#define NA 100000
#define NCLS 80
#define NC 79          // classes excluding background (IGNORE=0)
#define PERF 500
#define PROP 100

__device__ __forceinline__ uint32_t f2key(float s) {
  uint32_t b = __float_as_uint(s);
  return (b & 0x80000000u) ? ~b : (b | 0x80000000u);
}
__device__ __forceinline__ float key2f(uint32_t k) {
  uint32_t b = (k & 0x80000000u) ? (k ^ 0x80000000u) : ~k;
  return __uint_as_float(b);
}

// ---------------- Kernel 1: decode boxes ----------------
__global__ __launch_bounds__(256) void decode_kernel(
    const float* __restrict__ bbox_pred, const float* __restrict__ anchors,
    float* __restrict__ boxes) {
#pragma clang fp contract(off)
  int i = blockIdx.x * blockDim.x + threadIdx.x;
  if (i >= NB * NA) return;
  int a = i % NA;
  float4 d = ((const float4*)bbox_pred)[i];
  float4 an = ((const float4*)anchors)[a];
  const float MAXR = 4.135166556742356f;  // |log(16/1000)|
  float dw = fminf(fmaxf(d.z, -MAXR), MAXR);
  float dh = fminf(fmaxf(d.w, -MAXR), MAXR);
  float pw = an.z - an.x, ph = an.w - an.y;
  float px = (an.x + an.z) * 0.5f, py = (an.y + an.w) * 0.5f;
  float gw = pw * expf(dw), gh = ph * expf(dh);
  float gx = px + pw * d.x, gy = py + ph * d.y;
  float4 o;
  o.x = fminf(fmaxf(gx - gw * 0.5f, 0.0f), 1.0f);
  o.y = fminf(fmaxf(gy - gh * 0.5f, 0.0f), 1.0f);
  o.z = fminf(fmaxf(gx + gw * 0.5f, 0.0f), 1.0f);
  o.w = fminf(fmaxf(gy + gh * 0.5f, 0.0f), 1.0f);
  ((float4*)boxes)[i] = o;
}

// ---------------- Kernel 2: per-(image,class) exact top-500 (sorted, stable) ----------------
__global__ __launch_bounds__(1024) void topk_kernel(
    const float* __restrict__ y_pred, float* __restrict__ vals,
    int* __restrict__ aidx) {
  int blk = blockIdx.x;
  int b = blk / NC, ci = blk % NC, c = ci + 1;
  const float* sp = y_pred + (size_t)b * NA * NCLS + c;
  __shared__ uint32_t hist[2048];
  __shared__ unsigned long long buf[1024];
  __shared__ uint32_t s_lo, s_prefix, s_cnt;
  int tid = threadIdx.x;

  // pass 1: key[31:21]
  for (int i = tid; i < 2048; i += 1024) hist[i] = 0;
  __syncthreads();
  for (int a = tid; a < NA; a += 1024) {
    float v = sp[(size_t)a * NCLS];
    float s = v > 0.05f ? v : -1.0f;
    atomicAdd(&hist[f2key(s) >> 21], 1u);
  }
  __syncthreads();
  if (tid == 0) {
    uint32_t cum = 0; int t = 2047;
    for (;; --t) { uint32_t h = hist[t]; if (cum + h >= PERF || t == 0) break; cum += h; }
    s_lo = cum; s_prefix = (uint32_t)t;
  }
  __syncthreads();
  uint32_t above1 = s_lo, t1 = s_prefix;

  // pass 2: key[20:10]
  for (int i = tid; i < 2048; i += 1024) hist[i] = 0;
  __syncthreads();
  for (int a = tid; a < NA; a += 1024) {
    float v = sp[(size_t)a * NCLS];
    float s = v > 0.05f ? v : -1.0f;
    uint32_t k = f2key(s);
    if ((k >> 21) == t1) atomicAdd(&hist[(k >> 10) & 0x7FF], 1u);
  }
  __syncthreads();
  if (tid == 0) {
    uint32_t cum = above1; int t = 2047;
    for (;; --t) { uint32_t h = hist[t]; if (cum + h >= PERF || t == 0) break; cum += h; }
    s_lo = cum; s_prefix = (t1 << 11) | (uint32_t)t;
  }
  __syncthreads();
  uint32_t above2 = s_lo, p22 = s_prefix;

  // pass 3: key[9:0]
  for (int i = tid; i < 2048; i += 1024) hist[i] = 0;
  __syncthreads();
  for (int a = tid; a < NA; a += 1024) {
    float v = sp[(size_t)a * NCLS];
    float s = v > 0.05f ? v : -1.0f;
    uint32_t k = f2key(s);
    if ((k >> 10) == p22) atomicAdd(&hist[k & 0x3FF], 1u);
  }
  __syncthreads();
  if (tid == 0) {
    uint32_t cum = above2; int t = 1023;
    for (;; --t) { uint32_t h = hist[t]; if (cum + h >= PERF || t == 0) break; cum += h; }
    s_lo = (p22 << 10) | (uint32_t)t;  // exact 32-bit cutoff key
    s_cnt = 0;
  }
  __syncthreads();
  uint32_t cutoff = s_lo;
  buf[tid] = 0;
  __syncthreads();
  // collect all >= cutoff (count in [500, 500+ties))
  for (int a = tid; a < NA; a += 1024) {
    float v = sp[(size_t)a * NCLS];
    float s = v > 0.05f ? v : -1.0f;
    uint32_t k = f2key(s);
    if (k >= cutoff) {
      uint32_t p = atomicAdd(&s_cnt, 1u);
      if (p < 1024) buf[p] = ((unsigned long long)k << 32) | (uint32_t)(~(uint32_t)a);
    }
  }
  __syncthreads();
  // bitonic sort 1024 descending: key desc, then idx asc (via ~idx)
  for (uint32_t kk = 2; kk <= 1024; kk <<= 1)
    for (uint32_t j = kk >> 1; j > 0; j >>= 1) {
      __syncthreads();
      uint32_t i = tid, ixj = i ^ j;
      if (ixj > i) {
        unsigned long long x = buf[i], y = buf[ixj];
        if (((i & kk) == 0) ? (x < y) : (x > y)) { buf[i] = y; buf[ixj] = x; }
      }
    }
  __syncthreads();
  if (tid < PERF) {
    unsigned long long e = buf[tid];
    vals[(size_t)blk * PERF + tid] = key2f((uint32_t)(e >> 32));
    aidx[(size_t)blk * PERF + tid] = (int)(~(uint32_t)e);
  }
}

// ---------------- Kernel 3: greedy NMS per (image,class) ----------------
__global__ __launch_bounds__(256) void nms_kernel(
    const float* __restrict__ boxes, float* __restrict__ vals,
    const int* __restrict__ aidx) {
#pragma clang fp contract(off)
  int blk = blockIdx.x;
  int b = blk / NC;
  __shared__ float4 sb[PERF];
  __shared__ float sv[PERF];
  __shared__ unsigned long long smask[PERF][8];
  __shared__ unsigned long long skept[8];
  int tid = threadIdx.x;
  for (int i = tid; i < PERF; i += 256) {
    sv[i] = vals[(size_t)blk * PERF + i];
    int a = aidx[(size_t)blk * PERF + i];
    sb[i] = ((const float4*)boxes)[(size_t)b * NA + a];
  }
  __syncthreads();
  // symmetric IoU > 0.5 bitmask
  for (int i = tid; i < PERF; i += 256) {
    float4 bi = sb[i];
    float areai = (bi.z - bi.x) * (bi.w - bi.y);
    unsigned long long m[8] = {0, 0, 0, 0, 0, 0, 0, 0};
    for (int j = 0; j < PERF; ++j) {
      float4 bj = sb[j];
      float lx = fmaxf(bi.x, bj.x), ly = fmaxf(bi.y, bj.y);
      float rx = fminf(bi.z, bj.z), ry = fminf(bi.w, bj.w);
      float w = fmaxf(rx - lx, 0.0f), h = fmaxf(ry - ly, 0.0f);
      float inter = w * h;
      float areaj = (bj.z - bj.x) * (bj.w - bj.y);
      float uni = areai + areaj - inter;
      float iou = inter / fmaxf(uni, 1e-9f);
      if (iou > 0.5f) m[j >> 6] |= 1ull << (j & 63);
    }
    for (int w8 = 0; w8 < 8; ++w8) smask[i][w8] = m[w8];
  }
  __syncthreads();
  // greedy scan on wave 0: lanes 0..7 own kept-bit words
  if (tid < 64) {
    unsigned long long kept = 0;
    int lane = tid;
    for (int i = 0; i < PERF; ++i) {
      int pred = (lane < 8) && ((smask[i][lane] & kept) != 0ull);
      int sup = __any(pred);
      bool keep = (sv[i] > 0.0f) && !sup;
      if (keep && lane == (i >> 6)) kept |= 1ull << (i & 63);
    }
    if (lane < 8) skept[lane] = kept;
  }
  __syncthreads();
  for (int i = tid; i < PERF; i += 256) {
    bool k = (skept[i >> 6] >> (i & 63)) & 1ull;
    vals[(size_t)blk * PERF + i] = k ? sv[i] : -1.0f;
  }
}

// ---------------- Kernel 4: per-image global top-100 + gather outputs ----------------
__global__ __launch_bounds__(1024) void final_kernel(
    const float* __restrict__ vals, const int* __restrict__ aidx,
    const float* __restrict__ y_pred, const float* __restrict__ boxes,
    float* __restrict__ out) {
  int b = blockIdx.x;
  const float* v = vals + (size_t)b * NC * PERF;
  const int N = NC * PERF;
  __shared__ uint32_t hist[2048];
  __shared__ unsigned long long buf[256];
  __shared__ uint32_t s_lo, s_prefix, s_cnt;
  __shared__ int s_anchor[PROP];
  int tid = threadIdx.x;

  // pass 1
  for (int i = tid; i < 2048; i += 1024) hist[i] = 0;
  __syncthreads();
  for (int i = tid; i < N; i += 1024) atomicAdd(&hist[f2key(v[i]) >> 21], 1u);
  __syncthreads();
  if (tid == 0) {
    uint32_t cum = 0; int t = 2047;
    for (;; --t) { uint32_t h = hist[t]; if (cum + h >= PROP || t == 0) break; cum += h; }
    s_lo = cum; s_prefix = (uint32_t)t;
  }
  __syncthreads();
  uint32_t above1 = s_lo, t1 = s_prefix;

  // pass 2
  for (int i = tid; i < 2048; i += 1024) hist[i] = 0;
  __syncthreads();
  for (int i = tid; i < N; i += 1024) {
    uint32_t k = f2key(v[i]);
    if ((k >> 21) == t1) atomicAdd(&hist[(k >> 10) & 0x7FF], 1u);
  }
  __syncthreads();
  if (tid == 0) {
    uint32_t cum = above1; int t = 2047;
    for (;; --t) { uint32_t h = hist[t]; if (cum + h >= PROP || t == 0) break; cum += h; }
    s_lo = cum; s_prefix = (t1 << 11) | (uint32_t)t;
  }
  __syncthreads();
  uint32_t above2 = s_lo, p22 = s_prefix;

  // pass 3
  for (int i = tid; i < 2048; i += 1024) hist[i] = 0;
  __syncthreads();
  for (int i = tid; i < N; i += 1024) {
    uint32_t k = f2key(v[i]);
    if ((k >> 10) == p22) atomicAdd(&hist[k & 0x3FF], 1u);
  }
  __syncthreads();
  if (tid == 0) {
    uint32_t cum = above2; int t = 1023;
    for (;; --t) { uint32_t h = hist[t]; if (cum + h >= PROP || t == 0) break; cum += h; }
    s_lo = (p22 << 10) | (uint32_t)t;
    s_cnt = 0;
  }
  __syncthreads();
  uint32_t cutoff = s_lo;
  if (tid < 256) buf[tid] = 0;
  __syncthreads();
  for (int i = tid; i < N; i += 1024) {
    uint32_t k = f2key(v[i]);
    if (k >= cutoff) {
      uint32_t p = atomicAdd(&s_cnt, 1u);
      if (p < 256) buf[p] = ((unsigned long long)k << 32) | (uint32_t)(~(uint32_t)i);
    }
  }
  __syncthreads();
  for (uint32_t kk = 2; kk <= 256; kk <<= 1)
    for (uint32_t j = kk >> 1; j > 0; j >>= 1) {
      __syncthreads();
      if (tid < 256) {
        uint32_t i = tid, ixj = i ^ j;
        if (ixj > i) {
          unsigned long long x = buf[i], y = buf[ixj];
          if (((i & kk) == 0) ? (x < y) : (x > y)) { buf[i] = y; buf[ixj] = x; }
        }
      }
    }
  __syncthreads();
  if (tid < PROP) {
    unsigned long long e = buf[tid];
    float val = key2f((uint32_t)(e >> 32));
    uint32_t f = ~(uint32_t)e;
    int anchor = -1;
    if (val > 0.0f) anchor = aidx[(size_t)b * NC * PERF + f];
    s_anchor[tid] = anchor;
  }
  __syncthreads();
  float* out_scores = out;
  float* out_boxes = out + (size_t)NB * PROP * NCLS;
  if (tid < PROP) {
    int anchor = s_anchor[tid];
    float4 bx = make_float4(0.0f, 0.0f, 0.0f, 0.0f);
    if (anchor >= 0) bx = ((const float4*)boxes)[(size_t)b * NA + anchor];
    ((float4*)out_boxes)[b * PROP + tid] = bx;
  }
  for (int e2 = tid; e2 < PROP * NCLS; e2 += 1024) {
    int p = e2 / NCLS, c = e2 % NCLS;
    int anchor = s_anchor[p];
    out_scores[((size_t)b * PROP + p) * NCLS + c] =
        (anchor >= 0) ? y_pred[((size_t)b * NA + anchor) * NCLS + c] : 0.0f;
  }
}

extern "C" void kernel_launch(void* const* d_in, const int* in_sizes, int n_in,
                              void* d_out, int out_size, void* d_ws, size_t ws_size,
                              hipStream_t stream) {
  const float* y_pred = (const float*)d_in[0];     // [B,A,C] f32
  const float* bbox_pred = (const float*)d_in[1];  // [B,A,4] f32
  const float* anchors = (const float*)d_in[2];    // [A,4]   f32
  float* out = (float*)d_out;                      // scores[B,PROP,C] ++ boxes[B,PROP,4]

  float* boxes = (float*)d_ws;                          // NB*NA*4 floats
  float* vals = boxes + (size_t)NB * NA * 4;            // NB*NC*PERF floats
  int* aidx = (int*)(vals + (size_t)NB * NC * PERF);    // NB*NC*PERF ints

  hipLaunchKernelGGL(decode_kernel, dim3((NB * NA + 255) / 256), dim3(256), 0, stream,
                     bbox_pred, anchors, boxes);
  hipLaunchKernelGGL(topk_kernel, dim3(NB * NC), dim3(1024), 0, stream,
                     y_pred, vals, aidx);
  hipLaunchKernelGGL(nms_kernel, dim3(NB * NC), dim3(256), 0, stream,
                     boxes, vals, aidx);
  hipLaunchKernelGGL(final_kernel, dim3(NB), dim3(1024), 0, stream,
                     vals, aidx, y_pred, boxes, out);
}